// Round 1
// baseline (470.414 us; speedup 1.0000x reference)
//
#include <hip/hip_runtime.h>

#define NB 8192
#define COMPS 4096
#define DIM 768

typedef _Float16 half8_t __attribute__((ext_vector_type(8)));
typedef float floatx4 __attribute__((ext_vector_type(4)));
typedef unsigned short ushort4_t __attribute__((ext_vector_type(4)));
typedef unsigned short ushort8_t __attribute__((ext_vector_type(8)));

__device__ __forceinline__ unsigned long long pack_min(float v, int col) {
  unsigned u = __float_as_uint(v);
  u = (u & 0x80000000u) ? ~u : (u | 0x80000000u);
  return ((unsigned long long)u << 32) | (unsigned)col;
}

// ---------------- prep: fp32 -> fp16 hi/lo split ----------------
__global__ void k_prep_e(const float* __restrict__ e,
                         _Float16* __restrict__ ehi, _Float16* __restrict__ elo) {
  int id = blockIdx.x * 256 + threadIdx.x;     // float4 index
  float4 v = ((const float4*)e)[id];
  float x0 = v.x, x1 = v.y, x2 = v.z, x3 = v.w;
  ushort4_t h, l;
  float xs[4] = {x0, x1, x2, x3};
#pragma unroll
  for (int q = 0; q < 4; ++q) {
    _Float16 hh = (_Float16)xs[q];
    _Float16 ll = (_Float16)(xs[q] - (float)hh);
    h[q] = __builtin_bit_cast(unsigned short, hh);
    l[q] = __builtin_bit_cast(unsigned short, ll);
  }
  ((ushort4_t*)ehi)[id] = h;
  ((ushort4_t*)elo)[id] = l;
}

// contents: hi/lo split + fp32 row norms. 192 threads, 1 block per row.
__global__ void k_prep_c(const float* __restrict__ c,
                         _Float16* __restrict__ chi, _Float16* __restrict__ clo,
                         float* __restrict__ cnorm) {
  int i = blockIdx.x, t = threadIdx.x;         // 192 threads, 768 = 192*4
  float4 v = ((const float4*)c)[i * 192 + t];
  float xs[4] = {v.x, v.y, v.z, v.w};
  ushort4_t h, l;
  float s = 0.f;
#pragma unroll
  for (int q = 0; q < 4; ++q) {
    _Float16 hh = (_Float16)xs[q];
    _Float16 ll = (_Float16)(xs[q] - (float)hh);
    h[q] = __builtin_bit_cast(unsigned short, hh);
    l[q] = __builtin_bit_cast(unsigned short, ll);
    s = fmaf(xs[q], xs[q], s);
  }
  ((ushort4_t*)chi)[i * 192 + t] = h;
  ((ushort4_t*)clo)[i * 192 + t] = l;
#pragma unroll
  for (int o = 32; o; o >>= 1) s += __shfl_down(s, o);
  __shared__ float red[3];
  if ((t & 63) == 0) red[t >> 6] = s;
  __syncthreads();
  if (t == 0) cnorm[i] = red[0] + red[1] + red[2];
}

// ---------------- GEMM1: dist + fused argmin ----------------
// dist'[i][j] = ||c_j||^2 - 2 * e_i . c_j  via fp16 hi/lo split (hh+hl+lh)
__launch_bounds__(256)
__global__ void k_gemm1(const _Float16* __restrict__ ehi, const _Float16* __restrict__ elo,
                        const _Float16* __restrict__ chi, const _Float16* __restrict__ clo,
                        const float* __restrict__ cnorm,
                        unsigned long long* __restrict__ packed) {
  __shared__ _Float16 Ah[128 * 32], Al[128 * 32], Bh[128 * 32], Bl[128 * 32];
  int tid = threadIdx.x;
  int lane = tid & 63, w = tid >> 6;
  int wr = w >> 1, wc = w & 1;
  int g = lane >> 4, rl = lane & 15;
  int i0 = blockIdx.x * 128, j0 = blockIdx.y * 128;

  floatx4 acc[4][4] = {};

  for (int kt = 0; kt < DIM; kt += 32) {
    __syncthreads();
#pragma unroll
    for (int v = 0; v < 2; ++v) {
      int id = tid + 256 * v;
      int r = id >> 2, cch = id & 3;
      int cp = (cch + r + (r >> 2)) & 3;
      int lo_off = r * 32 + cp * 8;
      size_t ga = (size_t)(i0 + r) * DIM + kt + cch * 8;
      size_t gb = (size_t)(j0 + r) * DIM + kt + cch * 8;
      *(ushort8_t*)&Ah[lo_off] = *(const ushort8_t*)&ehi[ga];
      *(ushort8_t*)&Al[lo_off] = *(const ushort8_t*)&elo[ga];
      *(ushort8_t*)&Bh[lo_off] = *(const ushort8_t*)&chi[gb];
      *(ushort8_t*)&Bl[lo_off] = *(const ushort8_t*)&clo[gb];
    }
    __syncthreads();

    half8_t ah[4], al[4];
#pragma unroll
    for (int m = 0; m < 4; ++m) {
      int r = wr * 64 + m * 16 + rl;
      int slot = (g + r + (r >> 2)) & 3;
      ah[m] = *(half8_t*)&Ah[r * 32 + slot * 8];
      al[m] = *(half8_t*)&Al[r * 32 + slot * 8];
    }
#pragma unroll
    for (int n = 0; n < 4; ++n) {
      int r = wc * 64 + n * 16 + rl;
      int slot = (g + r + (r >> 2)) & 3;
      half8_t bh = *(half8_t*)&Bh[r * 32 + slot * 8];
      half8_t bl = *(half8_t*)&Bl[r * 32 + slot * 8];
#pragma unroll
      for (int m = 0; m < 4; ++m) {
        acc[m][n] = __builtin_amdgcn_mfma_f32_16x16x32_f16(ah[m], bh, acc[m][n], 0, 0, 0);
        acc[m][n] = __builtin_amdgcn_mfma_f32_16x16x32_f16(ah[m], bl, acc[m][n], 0, 0, 0);
        acc[m][n] = __builtin_amdgcn_mfma_f32_16x16x32_f16(al[m], bh, acc[m][n], 0, 0, 0);
      }
    }
  }

  // epilogue: per-row argmin over this block's 128 cols, merge via atomicMin
  float cn[4];
#pragma unroll
  for (int n = 0; n < 4; ++n) cn[n] = cnorm[j0 + wc * 64 + n * 16 + rl];

#pragma unroll
  for (int m = 0; m < 4; ++m) {
#pragma unroll
    for (int j = 0; j < 4; ++j) {
      int row = i0 + wr * 64 + m * 16 + g * 4 + j;
      float best = 3.0e38f;
      int bcol = 0;
#pragma unroll
      for (int n = 0; n < 4; ++n) {
        float d = fmaf(-2.0f, acc[m][n][j], cn[n]);
        int col = j0 + wc * 64 + n * 16 + rl;
        if (d < best) { best = d; bcol = col; }
      }
      unsigned long long pk = pack_min(best, bcol);
#pragma unroll
      for (int o = 1; o < 16; o <<= 1) {
        unsigned long long other = __shfl_xor(pk, o);
        if (other < pk) pk = other;
      }
      if (rl == 0) atomicMin(&packed[row], pk);
    }
  }
}

// ---------------- scatter: freq + per-comp sums ----------------
__global__ void k_scatter(const float* __restrict__ e,
                          const unsigned long long* __restrict__ packed,
                          float* __restrict__ freq, float* __restrict__ sums) {
  int i = blockIdx.x, t = threadIdx.x;
  int idx = (int)(packed[i] & 0xffffffffULL);
  if (t == 0) unsafeAtomicAdd(&freq[idx], 1.0f);
#pragma unroll
  for (int r = 0; r < 3; ++r) {
    int d = t + 256 * r;
    unsafeAtomicAdd(&sums[(size_t)idx * DIM + d], e[(size_t)i * DIM + d]);
  }
}

// ---------------- avg (transposed, fp16): avgT[d][j] ----------------
__global__ void k_avgt(const float* __restrict__ sums, const float* __restrict__ freq,
                       const float* __restrict__ cont, _Float16* __restrict__ avgT) {
  __shared__ float tile[64][65];
  int jb = blockIdx.x, db = blockIdx.y, t = threadIdx.x;
#pragma unroll
  for (int v = 0; v < 4; ++v) {
    int id = t + 256 * v;
    int r = id >> 4, c4 = id & 15;
    int j = jb * 64 + r;
    float f = freq[j];
    size_t o = (size_t)j * 192 + db * 16 + c4;
    float4 a;
    if (f > 0.f) {
      float4 s = ((const float4*)sums)[o];
      a.x = s.x / f; a.y = s.y / f; a.z = s.z / f; a.w = s.w / f;
    } else {
      a = ((const float4*)cont)[o];
    }
    tile[r][c4 * 4 + 0] = a.x; tile[r][c4 * 4 + 1] = a.y;
    tile[r][c4 * 4 + 2] = a.z; tile[r][c4 * 4 + 3] = a.w;
  }
  __syncthreads();
#pragma unroll
  for (int v = 0; v < 2; ++v) {
    int id = t + 256 * v;
    int drow = id >> 3, c8 = id & 7;
    int d = db * 64 + drow;
    ushort8_t h;
#pragma unroll
    for (int k = 0; k < 8; ++k) {
      _Float16 hv = (_Float16)tile[c8 * 8 + k][drow];
      h[k] = __builtin_bit_cast(unsigned short, hv);
    }
    *(ushort8_t*)&avgT[(size_t)d * COMPS + jb * 64 + c8 * 8] = h;
  }
}

// ---------------- weights fp16 + row sums ----------------
__global__ void k_expw(const float* __restrict__ gd, const float* __restrict__ sigma,
                       _Float16* __restrict__ W, float* __restrict__ wsum) {
  int i = blockIdx.x, t = threadIdx.x;
  float sg = sigma[0];
  float inv = -1.0f / (2.0f * sg * sg);
  float s = 0.f;
#pragma unroll
  for (int v = 0; v < 4; ++v) {
    int id = t + 256 * v;
    float4 gv = ((const float4*)gd)[(size_t)i * 1024 + id];
    float w0 = expf(gv.x * inv), w1 = expf(gv.y * inv);
    float w2 = expf(gv.z * inv), w3 = expf(gv.w * inv);
    s += (w0 + w1) + (w2 + w3);
    ushort4_t h;
    h[0] = __builtin_bit_cast(unsigned short, (_Float16)w0);
    h[1] = __builtin_bit_cast(unsigned short, (_Float16)w1);
    h[2] = __builtin_bit_cast(unsigned short, (_Float16)w2);
    h[3] = __builtin_bit_cast(unsigned short, (_Float16)w3);
    ((ushort4_t*)W)[(size_t)i * 1024 + id] = h;
  }
#pragma unroll
  for (int o = 32; o; o >>= 1) s += __shfl_down(s, o);
  __shared__ float red[4];
  if ((t & 63) == 0) red[t >> 6] = s;
  __syncthreads();
  if (t == 0) wsum[i] = (red[0] + red[1]) + (red[2] + red[3]);
}

// ---------------- GEMM2: num = W @ avg, fused update/where/delta ----------------
__launch_bounds__(256)
__global__ void k_gemm2(const _Float16* __restrict__ W, const _Float16* __restrict__ avgT,
                        const float* __restrict__ freq, const float* __restrict__ wsum,
                        const float* __restrict__ cont,
                        float* __restrict__ out, float* __restrict__ rowsq) {
  __shared__ _Float16 At[128 * 32], Bt[128 * 32];
  int tid = threadIdx.x;
  int lane = tid & 63, w = tid >> 6;
  int wr = w >> 1, wc = w & 1;
  int g = lane >> 4, rl = lane & 15;
  int i0 = blockIdx.x * 128, d0 = blockIdx.y * 128;

  floatx4 acc[4][4] = {};

  for (int kt = 0; kt < COMPS; kt += 32) {
    __syncthreads();
#pragma unroll
    for (int v = 0; v < 2; ++v) {
      int id = tid + 256 * v;
      int r = id >> 2, cch = id & 3;
      int cp = (cch + r + (r >> 2)) & 3;
      int lo_off = r * 32 + cp * 8;
      size_t ga = (size_t)(i0 + r) * COMPS + kt + cch * 8;
      size_t gb = (size_t)(d0 + r) * COMPS + kt + cch * 8;
      *(ushort8_t*)&At[lo_off] = *(const ushort8_t*)&W[ga];
      *(ushort8_t*)&Bt[lo_off] = *(const ushort8_t*)&avgT[gb];
    }
    __syncthreads();

    half8_t a[4];
#pragma unroll
    for (int m = 0; m < 4; ++m) {
      int r = wr * 64 + m * 16 + rl;
      int slot = (g + r + (r >> 2)) & 3;
      a[m] = *(half8_t*)&At[r * 32 + slot * 8];
    }
#pragma unroll
    for (int n = 0; n < 4; ++n) {
      int r = wc * 64 + n * 16 + rl;
      int slot = (g + r + (r >> 2)) & 3;
      half8_t b = *(half8_t*)&Bt[r * 32 + slot * 8];
#pragma unroll
      for (int m = 0; m < 4; ++m)
        acc[m][n] = __builtin_amdgcn_mfma_f32_16x16x32_f16(a[m], b, acc[m][n], 0, 0, 0);
    }
  }

#pragma unroll
  for (int m = 0; m < 4; ++m) {
#pragma unroll
    for (int j = 0; j < 4; ++j) {
      int i = i0 + wr * 64 + m * 16 + g * 4 + j;
      float f = freq[i];
      float ws = wsum[i];
      bool used = f > 0.f;
      float s = 0.f;
#pragma unroll
      for (int n = 0; n < 4; ++n) {
        int d = d0 + wc * 64 + n * 16 + rl;
        float cold = cont[(size_t)i * DIM + d];
        float nv = used ? (acc[m][n][j] / ws) : cold;
        out[1 + (size_t)i * DIM + d] = nv;
        float df = nv - cold;
        s = fmaf(df, df, s);
      }
#pragma unroll
      for (int o = 1; o < 16; o <<= 1) s += __shfl_xor(s, o);
      if (rl == 0) unsafeAtomicAdd(&rowsq[i], s);
    }
  }
}

// ---------------- delta = sum_j sqrt(rowsq[j]) ----------------
__global__ void k_delta(const float* __restrict__ rowsq, float* __restrict__ out) {
  int t = threadIdx.x;
  double s = 0.0;
  for (int j = t; j < COMPS; j += 256) s += sqrt((double)rowsq[j]);
#pragma unroll
  for (int o = 32; o; o >>= 1) s += __shfl_down(s, o);
  __shared__ double red[4];
  if ((t & 63) == 0) red[t >> 6] = s;
  __syncthreads();
  if (t == 0) out[0] = (float)(red[0] + red[1] + red[2] + red[3]);
}

extern "C" void kernel_launch(void* const* d_in, const int* in_sizes, int n_in,
                              void* d_out, int out_size, void* d_ws, size_t ws_size,
                              hipStream_t stream) {
  const float* e = (const float*)d_in[0];       // [8192, 768]
  const float* cont = (const float*)d_in[1];    // [64, 64, 768]
  const float* gd = (const float*)d_in[2];      // [4096, 4096]
  const float* sigma = (const float*)d_in[3];   // [1]
  float* out = (float*)d_out;                   // [1 + 4096*768]

  char* ws = (char*)d_ws;
  size_t off = 0;
  auto take = [&](size_t bytes) { char* p = ws + off; off += (bytes + 255) & ~(size_t)255; return p; };

  unsigned long long* packed = (unsigned long long*)take(NB * 8);
  float* freq  = (float*)take(COMPS * 4);
  float* wsum  = (float*)take(COMPS * 4);
  float* rowsq = (float*)take(COMPS * 4);
  float* cnorm = (float*)take(COMPS * 4);
  float* sums  = (float*)take((size_t)COMPS * DIM * 4);
  _Float16* avgT = (_Float16*)take((size_t)DIM * COMPS * 2);
  // union region: {ehi, elo, chi, clo} during GEMM1 phase; W afterwards
  char* U = take((size_t)NB * DIM * 2 * 2 + (size_t)COMPS * DIM * 2 * 2);
  _Float16* ehi = (_Float16*)U;
  _Float16* elo = (_Float16*)(U + (size_t)NB * DIM * 2);
  _Float16* chi = (_Float16*)(U + (size_t)NB * DIM * 4);
  _Float16* clo = (_Float16*)(U + (size_t)NB * DIM * 4 + (size_t)COMPS * DIM * 2);
  _Float16* W = (_Float16*)U;                    // aliases e/c halves (dead by then)

  hipMemsetAsync(packed, 0xFF, NB * 8, stream);
  hipMemsetAsync(freq, 0, COMPS * 4, stream);
  hipMemsetAsync(rowsq, 0, COMPS * 4, stream);
  hipMemsetAsync(sums, 0, (size_t)COMPS * DIM * 4, stream);

  k_prep_e<<<(NB * DIM / 4) / 256, 256, 0, stream>>>(e, ehi, elo);
  k_prep_c<<<COMPS, 192, 0, stream>>>(cont, chi, clo, cnorm);
  k_gemm1<<<dim3(NB / 128, COMPS / 128), 256, 0, stream>>>(ehi, elo, chi, clo, cnorm, packed);
  k_scatter<<<NB, 256, 0, stream>>>(e, packed, freq, sums);
  k_avgt<<<dim3(COMPS / 64, DIM / 64), 256, 0, stream>>>(sums, freq, cont, avgT);
  k_expw<<<COMPS, 256, 0, stream>>>(gd, sigma, W, wsum);
  k_gemm2<<<dim3(COMPS / 128, DIM / 128), 256, 0, stream>>>(W, avgT, freq, wsum, cont, out, rowsq);
  k_delta<<<1, 256, 0, stream>>>(rowsq, out);
}